// Round 1
// baseline (1405.153 us; speedup 1.0000x reference)
//
#include <hip/hip_runtime.h>
#include <math.h>

#define TT 2048      // tokens = B*S
#define HH 1024      // hidden
#define EE 8         // experts
#define II 4096      // intermediate
#define VV 32000     // vocab

typedef __attribute__((ext_vector_type(8))) short short8;
typedef __attribute__((ext_vector_type(4))) float f32x4;
typedef __attribute__((ext_vector_type(4))) unsigned short us4;

__device__ __forceinline__ unsigned short f2bf(float f) {
  union { float f; unsigned u; } v; v.f = f;
  unsigned r = (v.u + 0x7FFFu + ((v.u >> 16) & 1u)) >> 16;
  return (unsigned short)r;
}

// ---------------- K1: embedding gather + router + top2 + softmax ----------------
__global__ __launch_bounds__(64) void k_gather_router(
    const int* __restrict__ ids, const float* __restrict__ emb,
    const float* __restrict__ rw, const float* __restrict__ rb,
    unsigned short* __restrict__ xb, float* __restrict__ rweights,
    float* __restrict__ sel, int* __restrict__ counts, int* __restrict__ tok_list)
{
  const int t = blockIdx.x;
  const int lane = threadIdx.x;
  const int tok = ids[t];
  float p[EE];
#pragma unroll
  for (int e = 0; e < EE; e++) p[e] = 0.f;
#pragma unroll
  for (int c = 0; c < 4; c++) {
    const int h = c*256 + lane*4;
    const float4 xv = *(const float4*)&emb[tok*HH + h];
    us4 u;
    u[0] = f2bf(xv.x); u[1] = f2bf(xv.y); u[2] = f2bf(xv.z); u[3] = f2bf(xv.w);
    *(us4*)&xb[t*HH + h] = u;
    const float xs[4] = {xv.x, xv.y, xv.z, xv.w};
#pragma unroll
    for (int j = 0; j < 4; j++) {
      const float4 r0 = *(const float4*)&rw[(h+j)*EE];
      const float4 r1 = *(const float4*)&rw[(h+j)*EE + 4];
      p[0] += xs[j]*r0.x; p[1] += xs[j]*r0.y; p[2] += xs[j]*r0.z; p[3] += xs[j]*r0.w;
      p[4] += xs[j]*r1.x; p[5] += xs[j]*r1.y; p[6] += xs[j]*r1.z; p[7] += xs[j]*r1.w;
    }
  }
#pragma unroll
  for (int off = 32; off >= 1; off >>= 1) {
#pragma unroll
    for (int e = 0; e < EE; e++) p[e] += __shfl_xor(p[e], off, 64);
  }
  if (lane == 0) {
#pragma unroll
    for (int e = 0; e < EE; e++) p[e] += rb[e];
    int b0 = 0; float v0 = p[0];
#pragma unroll
    for (int e = 1; e < EE; e++) { if (p[e] > v0) { v0 = p[e]; b0 = e; } }
    int b1 = -1; float v1 = -3.0e38f;
#pragma unroll
    for (int e = 0; e < EE; e++) { if (e != b0 && p[e] > v1) { v1 = p[e]; b1 = e; } }
    const float ex = expf(v1 - v0);          // v0 >= v1 -> ex in (0,1]
    const float w0 = 1.f / (1.f + ex);
    const float w1v = ex * w0;
    rweights[t*2]   = w0;
    rweights[t*2+1] = w1v;
    sel[t*2]   = (float)b0;
    sel[t*2+1] = (float)b1;
    int j0 = atomicAdd(&counts[b0], 1); tok_list[b0*TT + j0] = t;
    int j1 = atomicAdd(&counts[b1], 1); tok_list[b1*TT + j1] = t;
  }
}

// ---------------- K1b: exclusive prefix scan of expert counts ----------------
__global__ void k_scan(const int* __restrict__ counts, int* __restrict__ offsets) {
  int s = 0;
  for (int e = 0; e < EE; e++) { offsets[e] = s; s += counts[e]; }
}

// ---------------- K2: expert GEMM1 + bias + exact gelu -> h_buf (bf16) ----------------
// C[Te, II] = gelu(X_e[Te, HH] @ w1[e] + b1[e]) ; A rows gathered via tok_list
__global__ __launch_bounds__(256) void k_ffn1(
    const unsigned short* __restrict__ xb, const float* __restrict__ w1,
    const float* __restrict__ b1, const int* __restrict__ counts,
    const int* __restrict__ offsets, const int* __restrict__ tok_list,
    unsigned short* __restrict__ hbuf)
{
  const int e = blockIdx.z;
  const int Te = counts[e];
  const int m0 = blockIdx.y * 128;
  if (m0 >= Te) return;
  const int n0 = blockIdx.x * 128;

  __shared__ short As[128*32];
  __shared__ short Bs[128*32];
  const int tid = threadIdx.x;
  const int lane = tid & 63, wid = tid >> 6;
  const int wm = (wid & 1)*64, wn = (wid >> 1)*64;
  const int l15 = lane & 15, quad = lane >> 4;
  const int arow = tid >> 1, akh = tid & 1;

  f32x4 acc[4][4];
  const f32x4 zf = {0.f, 0.f, 0.f, 0.f};
#pragma unroll
  for (int i = 0; i < 4; i++)
#pragma unroll
    for (int j = 0; j < 4; j++) acc[i][j] = zf;

  const int gr = m0 + arow;
  const int tok = (gr < Te) ? tok_list[e*TT + gr] : 0;
  const unsigned short* ap = xb + tok*HH + akh*16;
  const float* bp = w1 + (size_t)e*HH*II + (akh*16)*II + n0 + arow;
  short* aw = &As[arow*32 + akh*16];
  short* bw = &Bs[arow*32 + akh*16];

  for (int k0 = 0; k0 < HH; k0 += 32) {
    const int4 a0 = *(const int4*)(ap + k0);
    const int4 a1 = *(const int4*)(ap + k0 + 8);
    short8 bh0, bh1;
#pragma unroll
    for (int j = 0; j < 8; j++) bh0[j] = (short)f2bf(bp[(k0 + j)*II]);
#pragma unroll
    for (int j = 0; j < 8; j++) bh1[j] = (short)f2bf(bp[(k0 + 8 + j)*II]);
    *(int4*)aw = a0;
    *(int4*)(aw + 8) = a1;
    *(short8*)bw = bh0;
    *(short8*)(bw + 8) = bh1;
    __syncthreads();
    short8 af[4], bfr[4];
#pragma unroll
    for (int i = 0; i < 4; i++) af[i]  = *(const short8*)&As[(wm + i*16 + l15)*32 + quad*8];
#pragma unroll
    for (int i = 0; i < 4; i++) bfr[i] = *(const short8*)&Bs[(wn + i*16 + l15)*32 + quad*8];
#pragma unroll
    for (int i = 0; i < 4; i++)
#pragma unroll
      for (int j = 0; j < 4; j++)
        acc[i][j] = __builtin_amdgcn_mfma_f32_16x16x32_bf16(af[i], bfr[j], acc[i][j], 0, 0, 0);
    __syncthreads();
  }

  const int base = offsets[e];
#pragma unroll
  for (int i = 0; i < 4; i++) {
#pragma unroll
    for (int j = 0; j < 4; j++) {
      const int col = n0 + wn + j*16 + l15;
      const float bb = b1[e*II + col];
#pragma unroll
      for (int r = 0; r < 4; r++) {
        const int rl = m0 + wm + i*16 + quad*4 + r;
        if (rl < Te) {
          float v = acc[i][j][r] + bb;
          v = 0.5f * v * (1.f + erff(v * 0.70710678118654752f));
          hbuf[(size_t)(base + rl)*II + col] = f2bf(v);
        }
      }
    }
  }
}

// ---------------- K3: expert GEMM2 + bias, atomic combine into expert_out ----------------
// y[Te, HH] = H_e[Te, II] @ w2[e] + b2[e]; expert_out[tok] += y
__global__ __launch_bounds__(256) void k_ffn2(
    const unsigned short* __restrict__ hbuf, const float* __restrict__ w2,
    const float* __restrict__ b2, const int* __restrict__ counts,
    const int* __restrict__ offsets, const int* __restrict__ tok_list,
    float* __restrict__ eout)
{
  const int e = blockIdx.z;
  const int Te = counts[e];
  const int m0 = blockIdx.y * 128;
  if (m0 >= Te) return;
  const int n0 = blockIdx.x * 128;

  __shared__ short As[128*32];
  __shared__ short Bs[128*32];
  const int tid = threadIdx.x;
  const int lane = tid & 63, wid = tid >> 6;
  const int wm = (wid & 1)*64, wn = (wid >> 1)*64;
  const int l15 = lane & 15, quad = lane >> 4;
  const int arow = tid >> 1, akh = tid & 1;

  f32x4 acc[4][4];
  const f32x4 zf = {0.f, 0.f, 0.f, 0.f};
#pragma unroll
  for (int i = 0; i < 4; i++)
#pragma unroll
    for (int j = 0; j < 4; j++) acc[i][j] = zf;

  const int base = offsets[e];
  int hrow = base + m0 + arow;
  if (hrow > TT*2 - 1) hrow = TT*2 - 1;   // clamp: stay inside h_buf
  const unsigned short* ap = hbuf + (size_t)hrow*II + akh*16;
  const float* bp = w2 + (size_t)e*II*HH + (akh*16)*HH + n0 + arow;
  short* aw = &As[arow*32 + akh*16];
  short* bw = &Bs[arow*32 + akh*16];

  for (int k0 = 0; k0 < II; k0 += 32) {
    const int4 a0 = *(const int4*)(ap + k0);
    const int4 a1 = *(const int4*)(ap + k0 + 8);
    short8 bh0, bh1;
#pragma unroll
    for (int j = 0; j < 8; j++) bh0[j] = (short)f2bf(bp[(k0 + j)*HH]);
#pragma unroll
    for (int j = 0; j < 8; j++) bh1[j] = (short)f2bf(bp[(k0 + 8 + j)*HH]);
    *(int4*)aw = a0;
    *(int4*)(aw + 8) = a1;
    *(short8*)bw = bh0;
    *(short8*)(bw + 8) = bh1;
    __syncthreads();
    short8 af[4], bfr[4];
#pragma unroll
    for (int i = 0; i < 4; i++) af[i]  = *(const short8*)&As[(wm + i*16 + l15)*32 + quad*8];
#pragma unroll
    for (int i = 0; i < 4; i++) bfr[i] = *(const short8*)&Bs[(wn + i*16 + l15)*32 + quad*8];
#pragma unroll
    for (int i = 0; i < 4; i++)
#pragma unroll
      for (int j = 0; j < 4; j++)
        acc[i][j] = __builtin_amdgcn_mfma_f32_16x16x32_bf16(af[i], bfr[j], acc[i][j], 0, 0, 0);
    __syncthreads();
  }

#pragma unroll
  for (int i = 0; i < 4; i++) {
#pragma unroll
    for (int j = 0; j < 4; j++) {
      const int col = n0 + wn + j*16 + l15;
      const float bb = b2[e*HH + col];
#pragma unroll
      for (int r = 0; r < 4; r++) {
        const int rl = m0 + wm + i*16 + quad*4 + r;
        if (rl < Te) {
          const int tk = tok_list[e*TT + rl];
          atomicAdd(&eout[tk*HH + col], acc[i][j][r] + bb);
        }
      }
    }
  }
}

// ---------------- K4: expert_out f32 -> bf16 ----------------
__global__ __launch_bounds__(256) void k_combine(
    const float* __restrict__ eout, unsigned short* __restrict__ xoutb)
{
  const int i = (blockIdx.x*256 + threadIdx.x)*4;
  const float4 v = *(const float4*)&eout[i];
  us4 u;
  u[0] = f2bf(v.x); u[1] = f2bf(v.y); u[2] = f2bf(v.z); u[3] = f2bf(v.w);
  *(us4*)&xoutb[i] = u;
}

// ---------------- K5: LM head GEMM  C[TT,VV] = X[TT,HH] @ lm_w + lm_b ----------------
__global__ __launch_bounds__(256) void k_lmhead(
    const unsigned short* __restrict__ A, const float* __restrict__ B,
    const float* __restrict__ bias, float* __restrict__ out)
{
  __shared__ short As[128*32];
  __shared__ short Bs[128*32];
  const int tid = threadIdx.x;
  const int m0 = blockIdx.x*128, n0 = blockIdx.y*128;
  const int lane = tid & 63, wid = tid >> 6;
  const int wm = (wid & 1)*64, wn = (wid >> 1)*64;
  const int l15 = lane & 15, quad = lane >> 4;
  const int arow = tid >> 1, akh = tid & 1;

  f32x4 acc[4][4];
  const f32x4 zf = {0.f, 0.f, 0.f, 0.f};
#pragma unroll
  for (int i = 0; i < 4; i++)
#pragma unroll
    for (int j = 0; j < 4; j++) acc[i][j] = zf;

  const unsigned short* ap = A + (m0 + arow)*HH + akh*16;
  const float* bp = B + (akh*16)*VV + n0 + arow;
  short* aw = &As[arow*32 + akh*16];
  short* bw = &Bs[arow*32 + akh*16];

  for (int k0 = 0; k0 < HH; k0 += 32) {
    const int4 a0 = *(const int4*)(ap + k0);
    const int4 a1 = *(const int4*)(ap + k0 + 8);
    short8 bh0, bh1;
#pragma unroll
    for (int j = 0; j < 8; j++) bh0[j] = (short)f2bf(bp[(k0 + j)*VV]);
#pragma unroll
    for (int j = 0; j < 8; j++) bh1[j] = (short)f2bf(bp[(k0 + 8 + j)*VV]);
    *(int4*)aw = a0;
    *(int4*)(aw + 8) = a1;
    *(short8*)bw = bh0;
    *(short8*)(bw + 8) = bh1;
    __syncthreads();
    short8 af[4], bfr[4];
#pragma unroll
    for (int i = 0; i < 4; i++) af[i]  = *(const short8*)&As[(wm + i*16 + l15)*32 + quad*8];
#pragma unroll
    for (int i = 0; i < 4; i++) bfr[i] = *(const short8*)&Bs[(wn + i*16 + l15)*32 + quad*8];
#pragma unroll
    for (int i = 0; i < 4; i++)
#pragma unroll
      for (int j = 0; j < 4; j++)
        acc[i][j] = __builtin_amdgcn_mfma_f32_16x16x32_bf16(af[i], bfr[j], acc[i][j], 0, 0, 0);
    __syncthreads();
  }

#pragma unroll
  for (int i = 0; i < 4; i++) {
#pragma unroll
    for (int j = 0; j < 4; j++) {
      const int col = n0 + wn + j*16 + l15;
      const float bb = bias[col];
#pragma unroll
      for (int r = 0; r < 4; r++) {
        const int row = m0 + wm + i*16 + quad*4 + r;
        out[(size_t)row*VV + col] = acc[i][j][r] + bb;
      }
    }
  }
}

extern "C" void kernel_launch(void* const* d_in, const int* in_sizes, int n_in,
                              void* d_out, int out_size, void* d_ws, size_t ws_size,
                              hipStream_t stream) {
  const int*   ids = (const int*)d_in[0];
  const float* emb = (const float*)d_in[1];
  const float* rw  = (const float*)d_in[2];
  const float* rb  = (const float*)d_in[3];
  const float* w1  = (const float*)d_in[4];
  const float* b1  = (const float*)d_in[5];
  const float* w2  = (const float*)d_in[6];
  const float* b2  = (const float*)d_in[7];
  const float* lmw = (const float*)d_in[8];
  const float* lmb = (const float*)d_in[9];

  char* ws = (char*)d_ws;
  unsigned short* xb    = (unsigned short*)(ws);                       // 4 MB  [TT,HH] bf16
  unsigned short* xoutb = (unsigned short*)(ws + (size_t)4*1024*1024); // 4 MB  [TT,HH] bf16
  float*          eout  = (float*)(ws + (size_t)8*1024*1024);          // 8 MB  [TT,HH] f32
  unsigned short* hbuf  = (unsigned short*)(ws + (size_t)16*1024*1024);// 32 MB [TT*2,II] bf16
  int* counts   = (int*)(ws + (size_t)50*1024*1024);                   // 8 ints
  int* offsets  = counts + 16;                                          // 8 ints
  int* tok_list = counts + 32;                                          // EE*TT ints

  float* logits   = (float*)d_out;
  float* rweights = logits + (size_t)TT*VV;   // 65,536,000
  float* sel      = rweights + TT*2;

  hipMemsetAsync(counts, 0, 64, stream);
  hipMemsetAsync(eout, 0, (size_t)TT*HH*sizeof(float), stream);

  k_gather_router<<<TT, 64, 0, stream>>>(ids, emb, rw, rb, xb, rweights, sel, counts, tok_list);
  k_scan<<<1, 1, 0, stream>>>(counts, offsets);
  k_ffn1<<<dim3(II/128, TT/128, EE), 256, 0, stream>>>(xb, w1, b1, counts, offsets, tok_list, hbuf);
  k_ffn2<<<dim3(HH/128, TT/128, EE), 256, 0, stream>>>(hbuf, w2, b2, counts, offsets, tok_list, eout);
  k_combine<<<TT*HH/1024, 256, 0, stream>>>(eout, xoutb);
  k_lmhead<<<dim3(TT/128, VV/128), 256, 0, stream>>>(xoutb, lmw, lmb, logits);
}